// Round 10
// baseline (341.986 us; speedup 1.0000x reference)
//
#include <hip/hip_runtime.h>

// Problem constants (match reference setup_inputs)
#define N_NODES 50000
#define N_EDGES 800000
#define F_INF   64
#define C_CH    100
#define T_OUT   8

typedef unsigned short u16;
typedef unsigned int   u32;
typedef __attribute__((ext_vector_type(8))) short bf16x8;
typedef __attribute__((ext_vector_type(4))) float f32x4;

__device__ __forceinline__ float sigmoidf_(float x) {
    return 1.0f / (1.0f + __expf(-x));
}
__device__ __forceinline__ float tanhf_(float x) {
    return 1.0f - 2.0f / (__expf(2.0f * x) + 1.0f);
}
__device__ __forceinline__ u16 f2bf(float f) {
    union { float f; u32 u; } v; v.f = f;
    u32 u = v.u;
    u += 0x7FFF + ((u >> 16) & 1);   // RNE
    return (u16)(u >> 16);
}
__device__ __forceinline__ float bf2f(u16 h) {
    union { u32 u; float f; } v; v.u = ((u32)h) << 16;
    return v.f;
}

// ---------------------------------------------------------------------------
// k_prep: fused (a) in-degree histogram, (b) x->bf16, (c) weight prep.
// Wgru padded to [4][128][128] (rows 100..127 zero) for branchless B-loads.
// ---------------------------------------------------------------------------
#define HIST_B 3125                     // 800000/256
#define XBF_B  1563                     // ceil(400000/256)
#define WGRU_ELEMS (4 * 128 * 128)      // 65536
#define WL_ELEMS   (4 * 64 * 192)       // 49152
#define WP_B  ((WGRU_ELEMS + WL_ELEMS + 255) / 256)   // 448
__global__ void k_prep(const int* __restrict__ ei, const float* __restrict__ x,
                       const float* __restrict__ ggc, const float* __restrict__ gwih,
                       const float* __restrict__ gwhh,
                       const float* __restrict__ lwih, const float* __restrict__ lwhh,
                       int* __restrict__ deg, u16* __restrict__ xbf,
                       u16* __restrict__ Wgru, u16* __restrict__ Wl) {
    int gb = blockIdx.x;
    if (gb < HIST_B) {
        int e = gb * 256 + threadIdx.x;
        if (e < N_EDGES) atomicAdd(&deg[ei[N_EDGES + e]], 1);
        return;
    }
    if (gb < HIST_B + XBF_B) {
        int idx = (gb - HIST_B) * 256 + threadIdx.x;
        if (idx >= N_NODES * F_INF / 8) return;
        float4 a = ((const float4*)x)[idx * 2];
        float4 b = ((const float4*)x)[idx * 2 + 1];
        uint4 p;
        p.x = (u32)f2bf(a.x) | ((u32)f2bf(a.y) << 16);
        p.y = (u32)f2bf(a.z) | ((u32)f2bf(a.w) << 16);
        p.z = (u32)f2bf(b.x) | ((u32)f2bf(b.y) << 16);
        p.w = (u32)f2bf(b.z) | ((u32)f2bf(b.w) << 16);
        ((uint4*)xbf)[idx] = p;
        return;
    }
    int idx = (gb - HIST_B - XBF_B) * 256 + threadIdx.x;
    if (idx < WGRU_ELEMS) {
        int g = idx >> 14;
        int r = idx & 16383;
        int c = r >> 7;            // 0..127 (valid < 100)
        int k = r & 127;
        float val = 0.0f;
        if (c < 100) {
            if (g < 3) {
                if (k < 64) {
                    const float* wr = gwih + (g * 100 + c) * 100;
                    const float* gr = ggc + k * 100;
                    float s = 0.0f;
#pragma unroll 4
                    for (int j = 0; j < 100; ++j) s += wr[j] * gr[j];
                    val = s;
                } else if (g < 2) {
                    val = gwhh[(g * 100 + c) * 100 + (k - 64)];
                }
            } else {
                if (k >= 64) val = gwhh[(200 + c) * 100 + (k - 64)];
            }
        }
        Wgru[idx] = f2bf(val);
    } else if (idx < WGRU_ELEMS + WL_ELEMS) {
        int i2 = idx - WGRU_ELEMS;
        int g = i2 / 12288;
        int r = i2 - g * 12288;
        int c = r / 192;
        int k = r - c * 192;
        int row = g * 64 + c;
        float val = 0.0f;
        if (k < 100) val = lwih[row * 100 + k];
        else if (k >= 128) val = lwhh[row * 64 + (k - 128)];
        Wl[i2] = f2bf(val);
    }
}

// ---------------------------------------------------------------------------
// CSR stage 2: exclusive prefix sum, LDS-staged coalesced loads, no spill.
// ---------------------------------------------------------------------------
#define SCAN_T 1024
#define SCAN_L 49
#define TILE   (512 * SCAN_L)   // 25088 elems
__global__ __launch_bounds__(SCAN_T) void k_scan(const int* __restrict__ deg,
                                                 int* __restrict__ rowptr,
                                                 int* __restrict__ cursor) {
    __shared__ int ld[TILE];
    __shared__ int s[SCAN_T];
    const int4* deg4 = (const int4*)deg;
    int4* ld4 = (int4*)ld;
    int t = threadIdx.x;

    for (int i = t; i < TILE / 4; i += SCAN_T) ld4[i] = deg4[i];
    __syncthreads();
    int tot = 0;
    if (t < 512) {
        int base = t * SCAN_L;
#pragma unroll 7
        for (int j = 0; j < SCAN_L; ++j) tot += ld[base + j];
    }
    __syncthreads();
    for (int i = t; i < TILE / 4; i += SCAN_T) {
        int g4 = TILE / 4 + i;
        ld4[i] = (g4 < N_NODES / 4) ? deg4[g4] : make_int4(0, 0, 0, 0);
    }
    __syncthreads();
    if (t >= 512) {
        int base = (t - 512) * SCAN_L;
#pragma unroll 7
        for (int j = 0; j < SCAN_L; ++j) tot += ld[base + j];
    }
    s[t] = tot;
    __syncthreads();
    for (int off = 1; off < SCAN_T; off <<= 1) {
        int v = (t >= off) ? s[t - off] : 0;
        __syncthreads();
        s[t] += v;
        __syncthreads();
    }
    int run = s[t] - tot;

    for (int i = t; i < TILE / 4; i += SCAN_T) ld4[i] = deg4[i];
    __syncthreads();
    if (t < 512) {
        int base = t * SCAN_L;
        for (int j = 0; j < SCAN_L; ++j) {
            int i = base + j;
            rowptr[i] = run;
            cursor[i] = run;
            run += ld[base + j];
        }
    }
    __syncthreads();
    for (int i = t; i < TILE / 4; i += SCAN_T) {
        int g4 = TILE / 4 + i;
        ld4[i] = (g4 < N_NODES / 4) ? deg4[g4] : make_int4(0, 0, 0, 0);
    }
    __syncthreads();
    if (t >= 512) {
        int base = (t - 512) * SCAN_L;
        for (int j = 0; j < SCAN_L; ++j) {
            int g = TILE + base + j;
            if (g < N_NODES) {
                rowptr[g] = run;
                cursor[g] = run;
                run += ld[base + j];
            }
        }
    }
    if (t == SCAN_T - 1) rowptr[N_NODES] = s[t];
}

// ---------------------------------------------------------------------------
// CSR stage 3: reorder, 4 edges per thread.  Edge packed to 4B:
// low 16 = src (N<65536), high 16 = wgt bf16.  Random scatter payload 4B;
// edges of one dst are contiguous (~16/line) -> L2 write merging.
// ---------------------------------------------------------------------------
#define QUART_E (N_EDGES / 4)
__global__ void k_reorder(const int* __restrict__ ei, const float* __restrict__ ew,
                          int* __restrict__ cursor, u32* __restrict__ edge) {
    int t = blockIdx.x * blockDim.x + threadIdx.x;
    if (t >= QUART_E) return;
    int e0 = t, e1 = t + QUART_E, e2 = t + 2 * QUART_E, e3 = t + 3 * QUART_E;
    int s0 = ei[e0], s1 = ei[e1], s2 = ei[e2], s3 = ei[e3];
    int d0 = ei[N_EDGES + e0], d1 = ei[N_EDGES + e1];
    int d2 = ei[N_EDGES + e2], d3 = ei[N_EDGES + e3];
    u32 w0 = f2bf(ew[e0]), w1 = f2bf(ew[e1]), w2 = f2bf(ew[e2]), w3 = f2bf(ew[e3]);
    int p0 = atomicAdd(&cursor[d0], 1);
    int p1 = atomicAdd(&cursor[d1], 1);
    int p2 = atomicAdd(&cursor[d2], 1);
    int p3 = atomicAdd(&cursor[d3], 1);
    edge[p0] = (u32)s0 | (w0 << 16);
    edge[p1] = (u32)s1 | (w1 << 16);
    edge[p2] = (u32)s2 | (w2 << 16);
    edge[p3] = (u32)s3 | (w3 << 16);
}

// ---------------------------------------------------------------------------
// Aggregate: wave per node, lane = channel (bf16 rows, 128B/edge gather).
// Packed u32 edges: uint4 metadata = 4 edges; 8 gathers in flight.
// ---------------------------------------------------------------------------
__global__ __launch_bounds__(256) void k_agg(
    const int* __restrict__ rowptr, const u32* __restrict__ edge,
    const u16* __restrict__ xbf, u16* __restrict__ xaggbf) {
    int node = blockIdx.x * 4 + (threadIdx.x >> 6);
    int lane = threadIdx.x & 63;
    if (node >= N_NODES) return;
    int e0 = rowptr[node];
    int e1 = rowptr[node + 1];
    float acc = 0.0f;
    int e = e0;
    while (e < e1 && (e & 3)) {   // align to uint4
        u32 ed = edge[e];
        acc += bf2f(xbf[(size_t)(ed & 0xFFFF) * F_INF + lane]) * bf2f((u16)(ed >> 16));
        ++e;
    }
    for (; e + 7 < e1; e += 8) {
        uint4 p0 = *(const uint4*)(edge + e);
        uint4 p1 = *(const uint4*)(edge + e + 4);
        float v0 = bf2f(xbf[(size_t)(p0.x & 0xFFFF) * F_INF + lane]);
        float v1 = bf2f(xbf[(size_t)(p0.y & 0xFFFF) * F_INF + lane]);
        float v2 = bf2f(xbf[(size_t)(p0.z & 0xFFFF) * F_INF + lane]);
        float v3 = bf2f(xbf[(size_t)(p0.w & 0xFFFF) * F_INF + lane]);
        float v4 = bf2f(xbf[(size_t)(p1.x & 0xFFFF) * F_INF + lane]);
        float v5 = bf2f(xbf[(size_t)(p1.y & 0xFFFF) * F_INF + lane]);
        float v6 = bf2f(xbf[(size_t)(p1.z & 0xFFFF) * F_INF + lane]);
        float v7 = bf2f(xbf[(size_t)(p1.w & 0xFFFF) * F_INF + lane]);
        acc += v0 * bf2f((u16)(p0.x >> 16));
        acc += v1 * bf2f((u16)(p0.y >> 16));
        acc += v2 * bf2f((u16)(p0.z >> 16));
        acc += v3 * bf2f((u16)(p0.w >> 16));
        acc += v4 * bf2f((u16)(p1.x >> 16));
        acc += v5 * bf2f((u16)(p1.y >> 16));
        acc += v6 * bf2f((u16)(p1.z >> 16));
        acc += v7 * bf2f((u16)(p1.w >> 16));
    }
    for (; e + 3 < e1; e += 4) {
        uint4 p0 = *(const uint4*)(edge + e);
        float v0 = bf2f(xbf[(size_t)(p0.x & 0xFFFF) * F_INF + lane]);
        float v1 = bf2f(xbf[(size_t)(p0.y & 0xFFFF) * F_INF + lane]);
        float v2 = bf2f(xbf[(size_t)(p0.z & 0xFFFF) * F_INF + lane]);
        float v3 = bf2f(xbf[(size_t)(p0.w & 0xFFFF) * F_INF + lane]);
        acc += v0 * bf2f((u16)(p0.x >> 16));
        acc += v1 * bf2f((u16)(p0.y >> 16));
        acc += v2 * bf2f((u16)(p0.z >> 16));
        acc += v3 * bf2f((u16)(p0.w >> 16));
    }
    for (; e < e1; ++e) {
        u32 ed = edge[e];
        acc += bf2f(xbf[(size_t)(ed & 0xFFFF) * F_INF + lane]) * bf2f((u16)(ed >> 16));
    }
    acc /= fmaxf((float)(e1 - e0), 1.0f);
    xaggbf[(size_t)node * F_INF + lane] = f2bf(acc);
}

// ---------------------------------------------------------------------------
// Fused GRU + LSTM + head via MFMA bf16.  Block = 256 thr (4 waves), 64 nodes.
// A1 [xagg|x] bf16 in LDS (stride 152 u16), A2 (stride 216), wave-ct
// specialization, padded Wgru, direct h1/c1 stores, stride-65 head overlay.
// LDS 52608 B -> 3 blocks/CU.
// ---------------------------------------------------------------------------
#define A1S 152
#define A2S 216
__global__ __launch_bounds__(256, 3) void k_fused(
    const u16* __restrict__ xaggbf, const u16* __restrict__ xbf,
    const float* __restrict__ h0, const float* __restrict__ c0,
    const u16* __restrict__ Wgru, const u16* __restrict__ Wl,
    const float* __restrict__ gbih, const float* __restrict__ gbhh,
    const float* __restrict__ lbih, const float* __restrict__ lbhh,
    const float* __restrict__ lw, const float* __restrict__ lb,
    float* __restrict__ out, float* __restrict__ h1, float* __restrict__ c1) {
    __shared__ char smem[52608];
    u16*   A1   = (u16*)(smem);
    u16*   A2   = (u16*)(smem + 19456);
    float* bias = (float*)(smem + 47104);
    float* bl   = (float*)(smem + 49504);
    float* lwf  = (float*)(smem + 50528);   // [k*8+t]
    float* lbs  = (float*)(smem + 52576);
    int tid = threadIdx.x;
    int n0 = blockIdx.x * 64;

    // ---- stage A1 cols 0..63: xagg bf16 ----
    for (int idx = tid; idx < 512; idx += 256) {
        int row = idx >> 3, ch = idx & 7;
        int n = n0 + row;
        uint4 v = make_uint4(0, 0, 0, 0);
        if (n < N_NODES) v = ((const uint4*)xaggbf)[n * 8 + ch];
        *(uint4*)(A1 + row * A1S + ch * 8) = v;
    }
    // ---- stage A1 cols 64..127: x bf16 ----
    for (int idx = tid; idx < 512; idx += 256) {
        int row = idx >> 3, ch = idx & 7;
        int n = n0 + row;
        uint4 v = make_uint4(0, 0, 0, 0);
        if (n < N_NODES) v = ((const uint4*)xbf)[n * 8 + ch];
        *(uint4*)(A1 + row * A1S + 64 + ch * 8) = v;
    }
    // ---- stage A2 cols 128..191: h0 fp32 -> bf16 ----
    for (int idx = tid; idx < 512; idx += 256) {
        int row = idx >> 3, ch = idx & 7;
        int n = n0 + row;
        uint4 p = make_uint4(0, 0, 0, 0);
        if (n < N_NODES) {
            float4 f0 = ((const float4*)h0)[n * 16 + ch * 2];
            float4 f1 = ((const float4*)h0)[n * 16 + ch * 2 + 1];
            p.x = (u32)f2bf(f0.x) | ((u32)f2bf(f0.y) << 16);
            p.y = (u32)f2bf(f0.z) | ((u32)f2bf(f0.w) << 16);
            p.z = (u32)f2bf(f1.x) | ((u32)f2bf(f1.y) << 16);
            p.w = (u32)f2bf(f1.z) | ((u32)f2bf(f1.w) << 16);
        }
        *(uint4*)((char*)A2 + row * 432 + 256 + ch * 16) = p;
    }
    // ---- zero A2 cols 100..127 ----
    for (int idx = tid; idx < 64 * 14; idx += 256) {
        int row = idx / 14, j = idx - row * 14;
        *(u32*)((char*)A2 + row * 432 + 200 + j * 4) = 0;
    }
    // ---- biases + head weights ----
    for (int idx = tid; idx < 600; idx += 256)
        bias[idx] = (idx < 300) ? gbih[idx] : gbhh[idx - 300];
    if (tid < 256) bl[tid] = lbih[tid] + lbhh[tid];
    for (int idx = tid; idx < 512; idx += 256) {
        int k = idx >> 3, t = idx & 7;
        lwf[idx] = lw[t * F_INF + k];
    }
    if (tid < 8) lbs[tid] = lb[tid];
    __syncthreads();

    int w = tid >> 6, lane = tid & 63, quad = lane >> 4, ln = lane & 15;

    // ================= GEMM1: GRU gates, wave handles ct = w, w+4 =========
    for (int ct = w; ct < 7; ct += 4) {
        f32x4 ar[4], az[4], an[4], ah[4];
#pragma unroll
        for (int mt = 0; mt < 4; ++mt) {
            ar[mt] = (f32x4){0.f, 0.f, 0.f, 0.f};
            az[mt] = ar[mt]; an[mt] = ar[mt]; ah[mt] = ar[mt];
        }
        int rb = (ct * 16 + ln) * 128 + quad * 8;   // padded 128 rows/gate
#pragma unroll
        for (int kt = 0; kt < 4; ++kt) {
            bf16x8 b0 = *(const bf16x8*)(Wgru + rb + kt * 32);
            bf16x8 b1 = *(const bf16x8*)(Wgru + 16384 + rb + kt * 32);
            bf16x8 b2 = *(const bf16x8*)(Wgru + 32768 + rb + kt * 32);
            bf16x8 b3 = *(const bf16x8*)(Wgru + 49152 + rb + kt * 32);
#pragma unroll
            for (int mt = 0; mt < 4; ++mt) {
                bf16x8 a = *(const bf16x8*)(A1 + (mt * 16 + ln) * A1S + kt * 32 + quad * 8);
                ar[mt] = __builtin_amdgcn_mfma_f32_16x16x32_bf16(a, b0, ar[mt], 0, 0, 0);
                az[mt] = __builtin_amdgcn_mfma_f32_16x16x32_bf16(a, b1, az[mt], 0, 0, 0);
                an[mt] = __builtin_amdgcn_mfma_f32_16x16x32_bf16(a, b2, an[mt], 0, 0, 0);
                ah[mt] = __builtin_amdgcn_mfma_f32_16x16x32_bf16(a, b3, ah[mt], 0, 0, 0);
            }
        }
        int c = ct * 16 + ln;
        if (c < 100) {
            float br = bias[c] + bias[300 + c];
            float bz = bias[100 + c] + bias[400 + c];
            float bn = bias[200 + c];
            float bh = bias[500 + c];
#pragma unroll
            for (int mt = 0; mt < 4; ++mt) {
#pragma unroll
                for (int reg = 0; reg < 4; ++reg) {
                    int m = mt * 16 + quad * 4 + reg;
                    float rv = sigmoidf_(ar[mt][reg] + br);
                    float zv = sigmoidf_(az[mt][reg] + bz);
                    float nv = tanhf_(an[mt][reg] + bn + rv * (ah[mt][reg] + bh));
                    float xp = (c < F_INF) ? bf2f(A1[m * A1S + 64 + c]) : 0.0f;
                    A2[m * A2S + c] = f2bf((1.0f - zv) * nv + zv * xp);
                }
            }
        }
    }
    __syncthreads();

    // ================= GEMM2: LSTM gates + epilogue + direct stores =======
    float h1v[4][4];
    {
        int ct = w;                       // 0..3
        int c = ct * 16 + ln;             // < 64
        float bi = bl[c], bff = bl[64 + c], bg = bl[128 + c], bo = bl[192 + c];
        f32x4 ai[4], af[4], ag[4], ao[4];
#pragma unroll
        for (int mt = 0; mt < 4; ++mt) {
            ai[mt] = (f32x4){0.f, 0.f, 0.f, 0.f};
            af[mt] = ai[mt]; ag[mt] = ai[mt]; ao[mt] = ai[mt];
        }
        int rb = (ct * 16 + ln) * 192 + quad * 8;
#pragma unroll
        for (int kt = 0; kt < 6; ++kt) {
            bf16x8 b0 = *(const bf16x8*)(Wl + rb + kt * 32);
            bf16x8 b1 = *(const bf16x8*)(Wl + 12288 + rb + kt * 32);
            bf16x8 b2 = *(const bf16x8*)(Wl + 2 * 12288 + rb + kt * 32);
            bf16x8 b3 = *(const bf16x8*)(Wl + 3 * 12288 + rb + kt * 32);
#pragma unroll
            for (int mt = 0; mt < 4; ++mt) {
                bf16x8 a = *(const bf16x8*)(A2 + (mt * 16 + ln) * A2S + kt * 32 + quad * 8);
                ai[mt] = __builtin_amdgcn_mfma_f32_16x16x32_bf16(a, b0, ai[mt], 0, 0, 0);
                af[mt] = __builtin_amdgcn_mfma_f32_16x16x32_bf16(a, b1, af[mt], 0, 0, 0);
                ag[mt] = __builtin_amdgcn_mfma_f32_16x16x32_bf16(a, b2, ag[mt], 0, 0, 0);
                ao[mt] = __builtin_amdgcn_mfma_f32_16x16x32_bf16(a, b3, ao[mt], 0, 0, 0);
            }
        }
#pragma unroll
        for (int mt = 0; mt < 4; ++mt) {
#pragma unroll
            for (int reg = 0; reg < 4; ++reg) {
                int m = mt * 16 + quad * 4 + reg;
                int n = n0 + m;
                float iv = sigmoidf_(ai[mt][reg] + bi);
                float fv = sigmoidf_(af[mt][reg] + bff);
                float gv = tanhf_(ag[mt][reg] + bg);
                float ov = sigmoidf_(ao[mt][reg] + bo);
                float c0v = (n < N_NODES) ? c0[(size_t)n * F_INF + c] : 0.0f;
                float cc = fv * c0v + iv * gv;
                float hh = ov * tanhf_(cc);
                h1v[mt][reg] = hh;
                if (n < N_NODES) {
                    c1[(size_t)n * F_INF + c] = cc;
                    h1[(size_t)n * F_INF + c] = hh;
                }
            }
        }
    }
    __syncthreads();   // A1/A2 dead; overlay begins

    float* h1s = (float*)smem;   // [64][65] floats = 16640 B (over A1)
    {
        int c = w * 16 + ln;
#pragma unroll
        for (int mt = 0; mt < 4; ++mt)
#pragma unroll
            for (int reg = 0; reg < 4; ++reg) {
                int m = mt * 16 + quad * 4 + reg;
                h1s[m * 65 + c] = h1v[mt][reg];
            }
    }
    __syncthreads();

    // ---- fused head: out[n,t] = relu(h1[n,:]) @ lw^T + lb ----
    for (int o = tid; o < 512; o += 256) {
        int nl = o & 63, t = o >> 6;   // t uniform per wave-instr
        float acc = lbs[t];
        const float* hr = h1s + nl * 65;
#pragma unroll 8
        for (int k = 0; k < F_INF; ++k)
            acc += fmaxf(hr[k], 0.0f) * lwf[k * 8 + t];
        int n = n0 + nl;
        if (n < N_NODES) out[(size_t)n * T_OUT + t] = acc;
    }
}

extern "C" void kernel_launch(void* const* d_in, const int* in_sizes, int n_in,
                              void* d_out, int out_size, void* d_ws, size_t ws_size,
                              hipStream_t stream) {
    const float* x     = (const float*)d_in[0];
    const int*   ei    = (const int*)d_in[1];
    const float* ew    = (const float*)d_in[2];
    const float* h0    = (const float*)d_in[3];
    const float* c0    = (const float*)d_in[4];
    const float* ggc   = (const float*)d_in[5];
    const float* gwih  = (const float*)d_in[6];
    const float* gwhh  = (const float*)d_in[7];
    const float* gbih  = (const float*)d_in[8];
    const float* gbhh  = (const float*)d_in[9];
    const float* lwih  = (const float*)d_in[10];
    const float* lwhh  = (const float*)d_in[11];
    const float* lbih  = (const float*)d_in[12];
    const float* lbhh  = (const float*)d_in[13];
    const float* lw    = (const float*)d_in[14];
    const float* lb    = (const float*)d_in[15];

    float* out = (float*)d_out;                  // [N, 8]
    float* h1  = out + (size_t)N_NODES * T_OUT;  // [N, 64]
    float* c1  = h1 + (size_t)N_NODES * F_INF;   // [N, 64]

    // workspace layout (bytes; all 16B aligned)
    char* ws = (char*)d_ws;
    u16*   xaggbf = (u16*)ws;                          // 6,400,000
    u16*   xbf    = (u16*)(ws + 6400000);              // 6,400,000
    u16*   Wgru   = (u16*)(ws + 12800000);             // 131,072 (padded)
    u16*   Wl     = (u16*)(ws + 12931072);             // 98,304
    u32*   edge   = (u32*)(ws + 13029376);             // 3,200,000 (packed 4B)
    int*   deg    = (int*)(ws + 13029376 + 3200000);   // 200,000
    int*   rowptr = deg + N_NODES;                     // 200,004
    int*   cursor = rowptr + N_NODES + 1;              // 200,000

    hipMemsetAsync(deg, 0, N_NODES * sizeof(int), stream);

    k_prep<<<HIST_B + XBF_B + WP_B, 256, 0, stream>>>(
        ei, x, ggc, gwih, gwhh, lwih, lwhh, deg, xbf, Wgru, Wl);
    k_scan<<<1, SCAN_T, 0, stream>>>(deg, rowptr, cursor);
    { int b = (QUART_E + 255) / 256;
      k_reorder<<<b, 256, 0, stream>>>(ei, ew, cursor, edge); }
    { int b = (N_NODES + 3) / 4;
      k_agg<<<b, 256, 0, stream>>>(rowptr, edge, xbf, xaggbf); }
    { int b = (N_NODES + 63) / 64;  // 782
      k_fused<<<b, 256, 0, stream>>>(xaggbf, xbf, h0, c0, Wgru, Wl,
                                     gbih, gbhh, lbih, lbhh, lw, lb,
                                     out, h1, c1); }
}